// Round 7
// baseline (113.370 us; speedup 1.0000x reference)
//
#include <hip/hip_runtime.h>
#include <stdint.h>

typedef _Float16 f16x8 __attribute__((ext_vector_type(8)));
typedef float f32x4 __attribute__((ext_vector_type(4)));
typedef unsigned int u32x4 __attribute__((ext_vector_type(4)));

#define T_OBS 50
#define PRED 12

// ws layout (ushort == f16 bits):
//   enc frags: [t<8][kt<5][lane<64][j<8]   = 20480
//   dec frags: +20480
//   fc  frags: [kt<4][lane<64][j<8]        = 2048
#define DEC_OFF 20480
#define FC_OFF  40960
#define WS_ELEMS 43008

// kappa (physical A-column label) -> m (hidden-unit C/D-slot label)
// chosen so C/D slots feed B-frag slots with zero cross-lane movement.
// (Verified end-to-end in R1/R6: passed, absmax <= 0.0156.)
__device__ __forceinline__ int unperm(int k) {
  return (k & 3) | (((k >> 3) & 3) << 2) | (((k >> 2) & 1) << 4) | (k & 0x60);
}

__global__ void prep_kernel(const float* __restrict__ Wih_e, const float* __restrict__ Whh_e,
                            const float* __restrict__ bih_e, const float* __restrict__ bhh_e,
                            const float* __restrict__ Wih_d, const float* __restrict__ Whh_d,
                            const float* __restrict__ bih_d, const float* __restrict__ bhh_d,
                            const float* __restrict__ fcW,
                            unsigned short* __restrict__ ws) {
  int idx = blockIdx.x * 256 + threadIdx.x;
  if (idx >= WS_ELEMS) return;
  float val = 0.0f;
  if (idx < FC_OFF) {
    const bool enc = idx < DEC_OFF;
    const int e = enc ? idx : idx - DEC_OFF;
    const int j = e & 7;
    const int lane = (e >> 3) & 63;
    const int rem = e >> 9;            // t*5 + kt
    const int kt = rem % 5;
    const int t = rem / 5;
    const int n = 16 * t + (lane & 15);
    const int kappa = 32 * kt + ((lane >> 4) << 3) + j;
    const float* Wih = enc ? Wih_e : Wih_d;
    const float* Whh = enc ? Whh_e : Whh_d;
    const float* bih = enc ? bih_e : bih_d;
    const float* bhh = enc ? bhh_e : bhh_d;
    if (kappa < 128)       val = Whh[n * 128 + unperm(kappa)];
    else if (kappa < 131)  val = Wih[n * 3 + (kappa - 128)];
    else if (kappa == 131) val = bih[n] + bhh[n];
    // kappa >= 132 -> 0 (padding)
  } else {
    const int e = idx - FC_OFF;
    const int j = e & 7;
    const int lane = (e >> 3) & 63;
    const int kt = e >> 9;             // 0..3 (h part only; fc bias added in VALU)
    const int o = lane & 15;
    const int kappa = 32 * kt + ((lane >> 4) << 3) + j;
    if (o < 3) val = fcW[o * 128 + unperm(kappa)];
  }
  _Float16 h = (_Float16)val;
  ws[idx] = __builtin_bit_cast(unsigned short, h);
}

__device__ __forceinline__ float tanh_fast(float v) {
  float e = __builtin_amdgcn_exp2f(v * 2.8853900817779268f);
  return __builtin_fmaf(-2.0f, __builtin_amdgcn_rcpf(1.0f + e), 1.0f);
}

__device__ __forceinline__ unsigned int pk2(float a, float b) {
  return __builtin_bit_cast(unsigned int, __builtin_amdgcn_cvt_pkrtz(a, b));
}

__device__ __forceinline__ f16x8 ldfrag(const unsigned short* p) {
  return __builtin_bit_cast(f16x8, *(const u32x4*)p);
}

__device__ __forceinline__ f16x8 mkxf(float a, float b, float c) {
  u32x4 u;
  u[0] = pk2(a, b);
  u[1] = pk2(c, 1.0f);
  u[2] = 0u;
  u[3] = 0u;                // upper k-slots must be ZERO (A is zero there; 0*NaN trap)
  return __builtin_bit_cast(f16x8, u);
}

// Pin the emitted interleave: N x (1 MFMA, 4 VALU). This is the single-wave
// in-order-issue fix: VALU/trans insts must sit BETWEEN MFMAs in program
// order or they can never overlap the matrix pipe (1 wave/SIMD, no TLP).
__device__ __forceinline__ void sgb_mix40() {
  #pragma unroll
  for (int i = 0; i < 40; ++i) {
    __builtin_amdgcn_sched_group_barrier(0x008, 1, 0);  // 1 MFMA
    __builtin_amdgcn_sched_group_barrier(0x002, 4, 0);  // 4 VALU
  }
}
__device__ __forceinline__ void sgb_mix44() {
  #pragma unroll
  for (int i = 0; i < 44; ++i) {
    __builtin_amdgcn_sched_group_barrier(0x008, 1, 0);
    __builtin_amdgcn_sched_group_barrier(0x002, 4, 0);
  }
}

// One wave owns ALL of M for TWO independent 16-seq streams; zero LDS/barriers.
// Encoder: 2-stage software pipeline, half-step offset:
//   [MFMA_Y(s) || tanh_X(s)] ; [MFMA_X(s+1) || tanh_Y(s)]
// with sched_group_barrier pinning the MFMA/VALU interleave inside each half.
// 256 blocks x 4 waves = 1024 waves = 1/SIMD, single batch.
__global__ __launch_bounds__(256, 1) void traj_kernel(
    const float* __restrict__ src, const unsigned short* __restrict__ ws,
    const float* __restrict__ fcb, float* __restrict__ out) {
  const int lane = (int)(threadIdx.x & 63u);
  const int w = (int)(threadIdx.x >> 6u);
  const int sX = blockIdx.x * 128 + w * 32 + (lane & 15);
  const int sY = sX + 16;
  const float* xpX = src + (size_t)(sX >> 6) * (T_OBS * 192) + (sX & 63) * 3;
  const float* xpY = src + (size_t)(sY >> 6) * (T_OBS * 192) + (sY & 63) * 3;

  f16x8 A[40];
  #pragma unroll
  for (int i = 0; i < 40; ++i)
    A[i] = ldfrag(ws + (size_t)(i * 64 + lane) * 8);

  f16x8 BfX[4], BfY[4];
  #pragma unroll
  for (int i = 0; i < 4; ++i) {
    u32x4 zz = (u32x4)0u;
    BfX[i] = __builtin_bit_cast(f16x8, zz);
    BfY[i] = __builtin_bit_cast(f16x8, zz);
  }
  f16x8 xfX = mkxf(xpX[0], xpX[1], xpX[2]);
  f16x8 xfY = mkxf(xpY[0], xpY[1], xpY[2]);

  const f32x4 z = (f32x4){0.f, 0.f, 0.f, 0.f};
  f32x4 aX[8], aY[8];

  auto MFMA_X = [&]() {
    #pragma unroll
    for (int t = 0; t < 8; ++t) {
      aX[t] = __builtin_amdgcn_mfma_f32_16x16x32_f16(A[t * 5 + 4], xfX, z, 0, 0, 0);
      #pragma unroll
      for (int kt = 0; kt < 4; ++kt)
        aX[t] = __builtin_amdgcn_mfma_f32_16x16x32_f16(A[t * 5 + kt], BfX[kt], aX[t], 0, 0, 0);
    }
  };
  auto MFMA_Y = [&]() {
    #pragma unroll
    for (int t = 0; t < 8; ++t) {
      aY[t] = __builtin_amdgcn_mfma_f32_16x16x32_f16(A[t * 5 + 4], xfY, z, 0, 0, 0);
      #pragma unroll
      for (int kt = 0; kt < 4; ++kt)
        aY[t] = __builtin_amdgcn_mfma_f32_16x16x32_f16(A[t * 5 + kt], BfY[kt], aY[t], 0, 0, 0);
    }
  };
  auto TANH_X = [&]() {
    #pragma unroll
    for (int kt = 0; kt < 4; ++kt) {
      u32x4 F;
      F[0] = pk2(tanh_fast(aX[2 * kt][0]),     tanh_fast(aX[2 * kt][1]));
      F[1] = pk2(tanh_fast(aX[2 * kt][2]),     tanh_fast(aX[2 * kt][3]));
      F[2] = pk2(tanh_fast(aX[2 * kt + 1][0]), tanh_fast(aX[2 * kt + 1][1]));
      F[3] = pk2(tanh_fast(aX[2 * kt + 1][2]), tanh_fast(aX[2 * kt + 1][3]));
      BfX[kt] = __builtin_bit_cast(f16x8, F);
    }
  };
  auto TANH_Y = [&]() {
    #pragma unroll
    for (int kt = 0; kt < 4; ++kt) {
      u32x4 F;
      F[0] = pk2(tanh_fast(aY[2 * kt][0]),     tanh_fast(aY[2 * kt][1]));
      F[1] = pk2(tanh_fast(aY[2 * kt][2]),     tanh_fast(aY[2 * kt][3]));
      F[2] = pk2(tanh_fast(aY[2 * kt + 1][0]), tanh_fast(aY[2 * kt + 1][1]));
      F[3] = pk2(tanh_fast(aY[2 * kt + 1][2]), tanh_fast(aY[2 * kt + 1][3]));
      BfY[kt] = __builtin_bit_cast(f16x8, F);
    }
  };

  // ---- encoder: software-pipelined, halves offset by one stream ----
  MFMA_X();                              // step 0, stream X (prologue)
  for (int s = 0; s < T_OBS - 1; ++s) {
    const float nX0 = xpX[(s + 1) * 192], nX1 = xpX[(s + 1) * 192 + 1], nX2 = xpX[(s + 1) * 192 + 2];
    // HALF A: MFMA_Y(s) || tanh_X(s)
    MFMA_Y();
    TANH_X();
    xfX = mkxf(nX0, nX1, nX2);
    sgb_mix40();
    const float nY0 = xpY[(s + 1) * 192], nY1 = xpY[(s + 1) * 192 + 1], nY2 = xpY[(s + 1) * 192 + 2];
    // HALF B: MFMA_X(s+1) || tanh_Y(s)
    MFMA_X();
    TANH_Y();
    xfY = mkxf(nY0, nY1, nY2);
    sgb_mix40();
  }
  // peeled s = 49: finish both streams; xfX/xfY stay x[49] = decoder input 0
  MFMA_Y();
  TANH_X();
  sgb_mix40();
  TANH_Y();

  // ---- decoder weights (anti-dep on last enc MFMA; loads overlap tanh tail) ----
  #pragma unroll
  for (int i = 0; i < 40; ++i)
    A[i] = ldfrag(ws + DEC_OFF + (size_t)(i * 64 + lane) * 8);
  f16x8 Afc[4];
  #pragma unroll
  for (int kt = 0; kt < 4; ++kt)
    Afc[kt] = ldfrag(ws + FC_OFF + (size_t)(kt * 64 + lane) * 8);
  const float fb0 = fcb[0], fb1 = fcb[1], fb2 = fcb[2];

  float* opX = out + (size_t)(sX >> 6) * (PRED * 192) + (sX & 63) * 3;
  float* opY = out + (size_t)(sY >> 6) * (PRED * 192) + (sY & 63) * 3;

  // ---- decoder: per-step pipeline [MFMA_X] ; [MFMA_Y+fcX || tanh_X] ; [tanh_Y+fcY] ----
  for (int p = 0; p < PRED; ++p) {
    MFMA_X();
    // interleave region: Y's 40 rnn MFMAs + X's 4 fc MFMAs vs X's tanh/fc VALU
    MFMA_Y();
    TANH_X();
    f32x4 pX = __builtin_amdgcn_mfma_f32_16x16x32_f16(Afc[0], BfX[0], z, 0, 0, 0);
    #pragma unroll
    for (int kt = 1; kt < 4; ++kt)
      pX = __builtin_amdgcn_mfma_f32_16x16x32_f16(Afc[kt], BfX[kt], pX, 0, 0, 0);
    const float pX0 = pX[0] + fb0, pX1 = pX[1] + fb1, pX2 = pX[2] + fb2;
    xfX = mkxf(pX0, pX1, pX2);
    sgb_mix44();
    // tail: Y's tanh + fc (no MFMA left to overlap)
    TANH_Y();
    f32x4 pY = __builtin_amdgcn_mfma_f32_16x16x32_f16(Afc[0], BfY[0], z, 0, 0, 0);
    #pragma unroll
    for (int kt = 1; kt < 4; ++kt)
      pY = __builtin_amdgcn_mfma_f32_16x16x32_f16(Afc[kt], BfY[kt], pY, 0, 0, 0);
    const float pY0 = pY[0] + fb0, pY1 = pY[1] + fb1, pY2 = pY[2] + fb2;
    xfY = mkxf(pY0, pY1, pY2);
    if (lane < 16) {
      opX[p * 192 + 0] = pX0; opX[p * 192 + 1] = pX1; opX[p * 192 + 2] = pX2;
      opY[p * 192 + 0] = pY0; opY[p * 192 + 1] = pY1; opY[p * 192 + 2] = pY2;
    }
  }
}

extern "C" void kernel_launch(void* const* d_in, const int* in_sizes, int n_in,
                              void* d_out, int out_size, void* d_ws, size_t ws_size,
                              hipStream_t stream) {
  const float* src   = (const float*)d_in[0];
  const float* Wih_e = (const float*)d_in[1];
  const float* Whh_e = (const float*)d_in[2];
  const float* bih_e = (const float*)d_in[3];
  const float* bhh_e = (const float*)d_in[4];
  const float* Wih_d = (const float*)d_in[5];
  const float* Whh_d = (const float*)d_in[6];
  const float* bih_d = (const float*)d_in[7];
  const float* bhh_d = (const float*)d_in[8];
  const float* fcW   = (const float*)d_in[9];
  const float* fcb   = (const float*)d_in[10];
  (void)in_sizes; (void)n_in; (void)out_size; (void)ws_size;

  unsigned short* ws = (unsigned short*)d_ws;

  prep_kernel<<<(WS_ELEMS + 255) / 256, 256, 0, stream>>>(
      Wih_e, Whh_e, bih_e, bhh_e, Wih_d, Whh_d, bih_d, bhh_d, fcW, ws);

  traj_kernel<<<256, 256, 0, stream>>>(src, ws, fcb, (float*)d_out);
}

// Round 8
// 107.825 us; speedup vs baseline: 1.0514x; 1.0514x over previous
//
#include <hip/hip_runtime.h>
#include <stdint.h>

typedef _Float16 f16x8 __attribute__((ext_vector_type(8)));
typedef float f32x4 __attribute__((ext_vector_type(4)));
typedef unsigned int u32x4 __attribute__((ext_vector_type(4)));

#define T_OBS 50
#define PRED 12

// ws layout (ushort == f16 bits):
//   enc frags: [t<8][kt<5][lane<64][j<8]   = 20480
//   dec frags: +20480
//   fc  frags: [kt<4][lane<64][j<8]        = 2048
#define DEC_OFF 20480
#define FC_OFF  40960
#define WS_ELEMS 43008

// kappa (physical A-column label) -> m (hidden-unit C/D-slot label)
// chosen so C/D slots feed B-frag slots with zero cross-lane movement.
// (Verified end-to-end in R1/R6: passed, absmax <= 0.0156.)
__device__ __forceinline__ int unperm(int k) {
  return (k & 3) | (((k >> 3) & 3) << 2) | (((k >> 2) & 1) << 4) | (k & 0x60);
}

__global__ void prep_kernel(const float* __restrict__ Wih_e, const float* __restrict__ Whh_e,
                            const float* __restrict__ bih_e, const float* __restrict__ bhh_e,
                            const float* __restrict__ Wih_d, const float* __restrict__ Whh_d,
                            const float* __restrict__ bih_d, const float* __restrict__ bhh_d,
                            const float* __restrict__ fcW,
                            unsigned short* __restrict__ ws) {
  int idx = blockIdx.x * 256 + threadIdx.x;
  if (idx >= WS_ELEMS) return;
  float val = 0.0f;
  if (idx < FC_OFF) {
    const bool enc = idx < DEC_OFF;
    const int e = enc ? idx : idx - DEC_OFF;
    const int j = e & 7;
    const int lane = (e >> 3) & 63;
    const int rem = e >> 9;            // t*5 + kt
    const int kt = rem % 5;
    const int t = rem / 5;
    const int n = 16 * t + (lane & 15);
    const int kappa = 32 * kt + ((lane >> 4) << 3) + j;
    const float* Wih = enc ? Wih_e : Wih_d;
    const float* Whh = enc ? Whh_e : Whh_d;
    const float* bih = enc ? bih_e : bih_d;
    const float* bhh = enc ? bhh_e : bhh_d;
    if (kappa < 128)       val = Whh[n * 128 + unperm(kappa)];
    else if (kappa < 131)  val = Wih[n * 3 + (kappa - 128)];
    else if (kappa == 131) val = bih[n] + bhh[n];
    // kappa >= 132 -> 0 (padding)
  } else {
    const int e = idx - FC_OFF;
    const int j = e & 7;
    const int lane = (e >> 3) & 63;
    const int kt = e >> 9;             // 0..3 (h part only; fc bias added in VALU)
    const int o = lane & 15;
    const int kappa = 32 * kt + ((lane >> 4) << 3) + j;
    if (o < 3) val = fcW[o * 128 + unperm(kappa)];
  }
  _Float16 h = (_Float16)val;
  ws[idx] = __builtin_bit_cast(unsigned short, h);
}

__device__ __forceinline__ float tanh_fast(float v) {
  float e = __builtin_amdgcn_exp2f(v * 2.8853900817779268f);
  return __builtin_fmaf(-2.0f, __builtin_amdgcn_rcpf(1.0f + e), 1.0f);
}

__device__ __forceinline__ unsigned int pk2(float a, float b) {
  return __builtin_bit_cast(unsigned int, __builtin_amdgcn_cvt_pkrtz(a, b));
}

__device__ __forceinline__ f16x8 ldfrag(const unsigned short* p) {
  return __builtin_bit_cast(f16x8, *(const u32x4*)p);
}

__device__ __forceinline__ f16x8 mkxf(float a, float b, float c) {
  u32x4 u;
  u[0] = pk2(a, b);
  u[1] = pk2(c, 1.0f);
  u[2] = 0u;
  u[3] = 0u;                // upper k-slots must be ZERO (A zero there; 0*NaN trap)
  return __builtin_bit_cast(f16x8, u);
}

// Block = 128 threads = ONE pair of waves sharing 16 seqs; M-split-2.
// Wave w owns m-tiles 4w..4w+3 (A = 20 frags = 80 VGPR) and produces B-frags
// kt={2w,2w+1}; the pair trades 2 frags each way through 8KB LDS with a
// single pair-local barrier (double-buffered). K-rotation (2w+lf)&3 keeps all
// register indices compile-time; own frags sit at lf=0,1, partner's at 2,3.
// 2048 blocks at <=128 VGPR -> 4 waves/SIMD, 16 waves/CU, EXACTLY one batch;
// pairs are phase-independent (no cross-pair sync) so stalls of one wave are
// covered by the other 3 on the SIMD.
__global__ __launch_bounds__(128, 4) void traj_kernel(
    const float* __restrict__ src, const unsigned short* __restrict__ ws,
    const float* __restrict__ fcb, float* __restrict__ out) {
  __shared__ unsigned short xch[2][2][2][64][8];  // [par][wave][frag][lane][j] = 8KB

  const int lane = (int)(threadIdx.x & 63u);
  const int w = (int)(threadIdx.x >> 6u);          // 0..1 (wave-in-pair)
  const int seq = blockIdx.x * 16 + (lane & 15);
  const int b = seq >> 6;
  const int a = seq & 63;

  // ---- A-frags for my 4 m-tiles, k-rotated: lf<4 -> kt=(2w+lf)&3, lf=4 -> x-tile ----
  f16x8 A[20];
  #pragma unroll
  for (int tl = 0; tl < 4; ++tl) {
    const int t = 4 * w + tl;
    #pragma unroll
    for (int lf = 0; lf < 5; ++lf) {
      const int kt = (lf < 4) ? ((2 * w + lf) & 3) : 4;
      A[tl * 5 + lf] = ldfrag(ws + (size_t)((t * 5 + kt) * 64 + lane) * 8);
    }
  }

  const float* xq = src + (size_t)b * (T_OBS * 192) + a * 3;
  float x0 = xq[0], x1 = xq[1], x2 = xq[2];
  xq += 192;

  f16x8 Bl[4];
  #pragma unroll
  for (int i = 0; i < 4; ++i) {
    u32x4 zz = (u32x4)0u;
    Bl[i] = __builtin_bit_cast(f16x8, zz);         // h0 = 0
  }
  f16x8 xf = mkxf(x0, x1, x2);

  const f32x4 z = (f32x4){0.f, 0.f, 0.f, 0.f};

  auto rnn_step = [&](int par) {
    f32x4 acc0, acc1, acc2, acc3;
    // x/bias tile first (independent of exchanged h)
    acc0 = __builtin_amdgcn_mfma_f32_16x16x32_f16(A[0 * 5 + 4], xf, z, 0, 0, 0);
    acc1 = __builtin_amdgcn_mfma_f32_16x16x32_f16(A[1 * 5 + 4], xf, z, 0, 0, 0);
    acc2 = __builtin_amdgcn_mfma_f32_16x16x32_f16(A[2 * 5 + 4], xf, z, 0, 0, 0);
    acc3 = __builtin_amdgcn_mfma_f32_16x16x32_f16(A[3 * 5 + 4], xf, z, 0, 0, 0);
    #pragma unroll
    for (int lf = 0; lf < 4; ++lf) {
      acc0 = __builtin_amdgcn_mfma_f32_16x16x32_f16(A[0 * 5 + lf], Bl[lf], acc0, 0, 0, 0);
      acc1 = __builtin_amdgcn_mfma_f32_16x16x32_f16(A[1 * 5 + lf], Bl[lf], acc1, 0, 0, 0);
      acc2 = __builtin_amdgcn_mfma_f32_16x16x32_f16(A[2 * 5 + lf], Bl[lf], acc2, 0, 0, 0);
      acc3 = __builtin_amdgcn_mfma_f32_16x16x32_f16(A[3 * 5 + lf], Bl[lf], acc3, 0, 0, 0);
    }
    // tanh + pack: my m-tiles (4w..4w+3) ARE B-frags kt=2w (tl0,1), 2w+1 (tl2,3)
    u32x4 F0, F1;
    F0[0] = pk2(tanh_fast(acc0[0]), tanh_fast(acc0[1]));
    F0[1] = pk2(tanh_fast(acc0[2]), tanh_fast(acc0[3]));
    F0[2] = pk2(tanh_fast(acc1[0]), tanh_fast(acc1[1]));
    F0[3] = pk2(tanh_fast(acc1[2]), tanh_fast(acc1[3]));
    F1[0] = pk2(tanh_fast(acc2[0]), tanh_fast(acc2[1]));
    F1[1] = pk2(tanh_fast(acc2[2]), tanh_fast(acc2[3]));
    F1[2] = pk2(tanh_fast(acc3[0]), tanh_fast(acc3[1]));
    F1[3] = pk2(tanh_fast(acc3[2]), tanh_fast(acc3[3]));
    *(u32x4*)&xch[par][w][0][lane][0] = F0;
    *(u32x4*)&xch[par][w][1][lane][0] = F1;
    __syncthreads();                               // pair-local (128-thread block)
    Bl[0] = __builtin_bit_cast(f16x8, F0);         // own frags: lf 0,1
    Bl[1] = __builtin_bit_cast(f16x8, F1);
    Bl[2] = ldfrag(&xch[par][w ^ 1][0][lane][0]);  // partner frags: lf 2,3
    Bl[3] = ldfrag(&xch[par][w ^ 1][1][lane][0]);
  };

  // ---- encoder: 50 steps, distance-1 x prefetch (clamped so xf ends = x[49]) ----
  for (int s = 0; s < T_OBS; ++s) {
    const float nx0 = xq[0], nx1 = xq[1], nx2 = xq[2];
    xq += (s < T_OBS - 2) ? 192 : 0;
    rnn_step(s & 1);
    if (s < T_OBS - 1) xf = mkxf(nx0, nx1, nx2);
  }

  // ---- decoder weights (same rotation) + fc frags ----
  #pragma unroll
  for (int tl = 0; tl < 4; ++tl) {
    const int t = 4 * w + tl;
    #pragma unroll
    for (int lf = 0; lf < 5; ++lf) {
      const int kt = (lf < 4) ? ((2 * w + lf) & 3) : 4;
      A[tl * 5 + lf] = ldfrag(ws + DEC_OFF + (size_t)((t * 5 + kt) * 64 + lane) * 8);
    }
  }
  f16x8 Afc[4];
  #pragma unroll
  for (int lf = 0; lf < 4; ++lf) {
    const int kt = (2 * w + lf) & 3;
    Afc[lf] = ldfrag(ws + FC_OFF + (size_t)(kt * 64 + lane) * 8);
  }
  const float fb0 = fcb[0], fb1 = fcb[1], fb2 = fcb[2];

  float* op = out + (size_t)b * (PRED * 192) + a * 3;

  // ---- decoder: 12 autoregressive steps ----
  for (int p = 0; p < PRED; ++p) {
    rnn_step(p & 1);
    // fc head (K=128) on the updated h; both waves compute (feedback needed),
    // only w==0 stores. Output rows 0..2 -> pf[0..2] on lanes 0..15.
    f32x4 pf = __builtin_amdgcn_mfma_f32_16x16x32_f16(Afc[0], Bl[0], z, 0, 0, 0);
    #pragma unroll
    for (int lf = 1; lf < 4; ++lf)
      pf = __builtin_amdgcn_mfma_f32_16x16x32_f16(Afc[lf], Bl[lf], pf, 0, 0, 0);
    const float p0 = pf[0] + fb0;
    const float p1 = pf[1] + fb1;
    const float p2 = pf[2] + fb2;
    if (w == 0 && lane < 16) {
      op[p * 192 + 0] = p0;
      op[p * 192 + 1] = p1;
      op[p * 192 + 2] = p2;
    }
    // feedback: valid on lanes 0..15 (the lanes whose x k-slots are read);
    // other lanes hold finite junk that multiplies A's zero columns.
    xf = mkxf(p0, p1, p2);
  }
}

extern "C" void kernel_launch(void* const* d_in, const int* in_sizes, int n_in,
                              void* d_out, int out_size, void* d_ws, size_t ws_size,
                              hipStream_t stream) {
  const float* src   = (const float*)d_in[0];
  const float* Wih_e = (const float*)d_in[1];
  const float* Whh_e = (const float*)d_in[2];
  const float* bih_e = (const float*)d_in[3];
  const float* bhh_e = (const float*)d_in[4];
  const float* Wih_d = (const float*)d_in[5];
  const float* Whh_d = (const float*)d_in[6];
  const float* bih_d = (const float*)d_in[7];
  const float* bhh_d = (const float*)d_in[8];
  const float* fcW   = (const float*)d_in[9];
  const float* fcb   = (const float*)d_in[10];
  (void)in_sizes; (void)n_in; (void)out_size; (void)ws_size;

  unsigned short* ws = (unsigned short*)d_ws;

  prep_kernel<<<(WS_ELEMS + 255) / 256, 256, 0, stream>>>(
      Wih_e, Whh_e, bih_e, bhh_e, Wih_d, Whh_d, bih_d, bhh_d, fcW, ws);

  // 32768 seqs / 16 per pair-block = 2048 blocks x 128 threads
  // = 4096 waves = 16/CU = 4/SIMD: exactly one resident batch.
  traj_kernel<<<2048, 128, 0, stream>>>(src, ws, fcb, (float*)d_out);
}